// Round 4
// baseline (500.252 us; speedup 1.0000x reference)
//
#include <hip/hip_runtime.h>

#define NB 8
#define ND 32
#define NHW (512*512)
#define NK 16
#define IGN 255

// per-image stats workspace layout (floats)
#define WS_S   1088
#define O_CNT  0      // counts[16]
#define O_VPIX 16     // # of valid (mask & !=IGN) pixels
#define O_SUM  32     // sums[16*32]
#define O_CEN  544    // centers[16*32]
#define O_PULL 1056   // pull partial sums[16]
#define O_PUSH 1072
#define O_REG  1073
#define O_VB   1074
#define O_NID  1075

#define IDP_OFF 65536          // byte offset of packed-id region in ws

// accum config: 1024 blocks, each 8 tiles of 256 pixels (contiguous 2048 px)
#define ATPB 256
#define TILE 256
#define ABLK 128
#define NTILES (NHW / (ABLK * TILE))   // 8

// pull config
#define PTPB 256
#define PCHUNKS 256
#define PPIX (NHW / PCHUNKS)   // 1024

__global__ __launch_bounds__(256) void k_zero(float* __restrict__ ws) {
    int i = blockIdx.x * blockDim.x + threadIdx.x;
    if (i < NB * WS_S) ws[i] = 0.f;
}

// Pass 1: global_load_lds-staged streaming (double-buffered, counted vmcnt),
// LDS->LDS segment-sum atomics. Each wave stages AND consumes its own 8
// d-rows -> no barriers in the main loop.
__global__ __launch_bounds__(ATPB) void k_accum(const float* __restrict__ pred,
                                                const int* __restrict__ inst,
                                                const unsigned char* __restrict__ msk,
                                                float* __restrict__ ws,
                                                unsigned char* __restrict__ idp) {
    __shared__ float buf[2][ND][TILE];   // 64 KB staging
    __shared__ float acc[2][17][33];     // copy=half-wave; stride 561 -> bank +17
    __shared__ float lcnt[2][17];
    const int tid = threadIdx.x;
    const int w = tid >> 6, l = tid & 63;
    const int c = l >> 5;
    const int b = blockIdx.y, chunk = blockIdx.x;

    for (int i = tid; i < 2 * 17 * 33; i += ATPB) ((float*)acc)[i] = 0.f;
    if (tid < 2 * 17) ((float*)lcnt)[tid] = 0.f;
    __syncthreads();

    const size_t img = (size_t)b * NHW;
    const float* pb = pred + (size_t)b * ND * NHW;
    const int base0 = chunk * (NTILES * TILE);

#define STAGE(CUR, T)                                                         \
    {                                                                         \
        const int pix0_ = base0 + (T) * TILE;                                 \
        _Pragma("unroll")                                                     \
        for (int q_ = 0; q_ < 8; ++q_) {                                      \
            const int d_ = 8 * w + q_;                                        \
            const float* src_ = pb + (size_t)d_ * NHW + pix0_ + 4 * l;        \
            __builtin_amdgcn_global_load_lds(                                 \
                (const __attribute__((address_space(1))) unsigned*)src_,      \
                (__attribute__((address_space(3))) unsigned*)&buf[CUR][d_][0],\
                16, 0, 0);                                                    \
        }                                                                     \
    }

    // prologue: ids first, then stage (so id use waits vmcnt(8), not 0)
    int4 iv = *(const int4*)(inst + img + base0 + 4 * l);
    unsigned mv = *(const unsigned*)(msk + img + base0 + 4 * l);
    STAGE(0, 0);

    float vcnt = 0.f;
    for (int t = 0; t < NTILES; ++t) {
        const int cur = t & 1;
        // decode tile-t ids (loaded last iteration)
        const int ida[4] = {iv.x, iv.y, iv.z, iv.w};
        int sid[4];
        #pragma unroll
        for (int p = 0; p < 4; ++p) {
            const bool m = (((mv >> (8 * p)) & 0xffu) != 0u) && (ida[p] != IGN);
            if (w == 0) vcnt += m ? 1.f : 0.f;
            sid[p] = (m && (unsigned)ida[p] < NK) ? ida[p] : NK;
        }
        if (w == 0) {
            uchar4 pk = {(unsigned char)sid[0], (unsigned char)sid[1],
                         (unsigned char)sid[2], (unsigned char)sid[3]};
            *(uchar4*)(idp + img + base0 + t * TILE + 4 * l) = pk;
            #pragma unroll
            for (int p = 0; p < 4; ++p) atomicAdd(&lcnt[c][sid[p]], 1.f);
        }
        // issue next tile (ids first, then 8 stages), keep 10 in flight
        if (t + 1 < NTILES) {
            const int nb0 = base0 + (t + 1) * TILE;
            iv = *(const int4*)(inst + img + nb0 + 4 * l);
            mv = *(const unsigned*)(msk + img + nb0 + 4 * l);
            STAGE(cur ^ 1, t + 1);
            asm volatile("s_waitcnt vmcnt(10)" ::: "memory");
        } else {
            asm volatile("s_waitcnt vmcnt(0)" ::: "memory");
        }
        __builtin_amdgcn_sched_barrier(0);
        // consume tile t: this wave's own 8 d-rows
        #pragma unroll
        for (int q = 0; q < 8; ++q) {
            const int d = 8 * w + q;
            const float4 v = *(const float4*)&buf[cur][d][4 * l];
            atomicAdd(&acc[c][sid[0]][d], v.x);
            atomicAdd(&acc[c][sid[1]][d], v.y);
            atomicAdd(&acc[c][sid[2]][d], v.z);
            atomicAdd(&acc[c][sid[3]][d], v.w);
        }
    }
#undef STAGE

    __syncthreads();
    float* wb = ws + b * WS_S;
    for (int i = tid; i < NK * ND; i += ATPB) {
        const int k = i >> 5, d = i & 31;
        atomicAdd(&wb[O_SUM + i], acc[0][k][d] + acc[1][k][d]);
    }
    if (tid < NK) atomicAdd(&wb[O_CNT + tid], lcnt[0][tid] + lcnt[1][tid]);
    if (w == 0) {
        #pragma unroll
        for (int off = 32; off > 0; off >>= 1) vcnt += __shfl_down(vcnt, off);
        if (l == 0) atomicAdd(&wb[O_VPIX], vcnt);
    }
}

__global__ __launch_bounds__(256) void k_centers(float* __restrict__ ws) {
    __shared__ float lc[NK][ND + 1];
    __shared__ float lcnt[NK];
    __shared__ float rsum[256], rcnt[256];
    const int tid = threadIdx.x;
    float* wb = ws + blockIdx.x * WS_S;

    if (tid < NK) lcnt[tid] = wb[O_CNT + tid];
    __syncthreads();
    for (int i = tid; i < NK * ND; i += 256) {
        int k = i >> 5, d = i & 31;
        float c = wb[O_SUM + i] / fmaxf(lcnt[k], 1.f);
        lc[k][d] = c;
        wb[O_CEN + i] = c;
    }
    __syncthreads();

    const int i = tid >> 4, j = tid & 15;
    const bool pm = (i != j) && (lcnt[i] > 0.f) && (lcnt[j] > 0.f);
    float sq = 0.f;
    #pragma unroll
    for (int d = 0; d < ND; ++d) { float df = lc[i][d] - lc[j][d]; sq += df * df; }
    float dm = sqrtf(pm ? sq : 1.f);
    float r = fmaxf(2.f * 1.5f - dm, 0.f);
    rsum[tid] = pm ? r * r : 0.f;
    rcnt[tid] = pm ? 1.f : 0.f;
    __syncthreads();
    for (int s = 128; s > 0; s >>= 1) {
        if (tid < s) { rsum[tid] += rsum[tid + s]; rcnt[tid] += rcnt[tid + s]; }
        __syncthreads();
    }

    if (tid == 0) {
        float nids = 0.f;
        for (int k = 0; k < NK; ++k) nids += (lcnt[k] > 0.f) ? 1.f : 0.f;
        float push = (nids > 1.f) ? rsum[0] / fmaxf(rcnt[0], 1.f) : 0.f;
        float reg = 0.f;
        for (int k = 0; k < NK; ++k) {
            if (lcnt[k] > 0.f) {
                float cs = 0.f;
                for (int d = 0; d < ND; ++d) cs += lc[k][d] * lc[k][d];
                reg += sqrtf(cs);
            }
        }
        reg /= fmaxf(nids, 1.f);
        wb[O_PUSH] = push;
        wb[O_REG] = reg;
        wb[O_VB] = (wb[O_VPIX] > 0.f) ? 1.f : 0.f;
        wb[O_NID] = nids;
    }
}

// Pass 2: float4 streaming + packed ids (measured ~50 us).
__global__ __launch_bounds__(PTPB) void k_pull(const float* __restrict__ pred,
                                               const unsigned char* __restrict__ idp,
                                               float* __restrict__ ws) {
    __shared__ float lc[17][ND + 1];   // row 16 = zeros (invalid)
    __shared__ float lp[2][NK];
    const int tid = threadIdx.x;
    // reversed global order vs k_accum: tail of pass-1 stream is L3-resident
    const int b = NB - 1 - blockIdx.y;
    const int chunk = PCHUNKS - 1 - blockIdx.x;
    const int half = (tid >> 5) & 1;
    float* wb = ws + b * WS_S;

    for (int i = tid; i < 17 * ND; i += PTPB)
        lc[i >> 5][i & 31] = (i < NK * ND) ? wb[O_CEN + i] : 0.f;
    if (tid < 2 * NK) ((float*)lp)[tid] = 0.f;
    __syncthreads();

    const size_t img = (size_t)b * NHW;
    const float* pb = pred + (size_t)b * ND * NHW;

    const int pix = chunk * PPIX + 4 * tid;
    const unsigned pk = *(const unsigned*)(idp + img + pix);
    const int id[4] = {(int)(pk & 0xff), (int)((pk >> 8) & 0xff),
                       (int)((pk >> 16) & 0xff), (int)(pk >> 24)};
    float sq[4] = {0.f, 0.f, 0.f, 0.f};
    #pragma unroll 8
    for (int d = 0; d < ND; ++d) {
        const float4 v = *(const float4*)(pb + (size_t)d * NHW + pix);
        float df0 = v.x - lc[id[0]][d];
        float df1 = v.y - lc[id[1]][d];
        float df2 = v.z - lc[id[2]][d];
        float df3 = v.w - lc[id[3]][d];
        sq[0] += df0 * df0; sq[1] += df1 * df1;
        sq[2] += df2 * df2; sq[3] += df3 * df3;
    }
    #pragma unroll
    for (int p = 0; p < 4; ++p) {
        if (id[p] < NK) {
            float r = fmaxf(sqrtf(sq[p]) - 0.5f, 0.f);
            atomicAdd(&lp[half][id[p]], r * r);
        }
    }
    __syncthreads();
    if (tid < NK) atomicAdd(&wb[O_PULL + tid], lp[0][tid] + lp[1][tid]);
}

__global__ void k_final(const float* __restrict__ ws, float* __restrict__ out) {
    const int tid = threadIdx.x;
    float contrib = 0.f, vb = 0.f;
    if (tid < NB) {
        const float* wb = ws + tid * WS_S;
        float nids = wb[O_NID];
        float pull = 0.f;
        for (int k = 0; k < NK; ++k) {
            float c = wb[O_CNT + k];
            if (c > 0.f) pull += wb[O_PULL + k] / fmaxf(c, 1.f);
        }
        pull /= fmaxf(nids, 1.f);
        vb = wb[O_VB];
        contrib = (pull + wb[O_PUSH] + 0.001f * wb[O_REG]) * vb;
    }
    #pragma unroll
    for (int off = 32; off > 0; off >>= 1) {
        contrib += __shfl_down(contrib, off);
        vb += __shfl_down(vb, off);
    }
    if (tid == 0) out[0] = (vb > 0.f) ? contrib / fmaxf(vb, 1.f) : 0.f;
}

extern "C" void kernel_launch(void* const* d_in, const int* in_sizes, int n_in,
                              void* d_out, int out_size, void* d_ws, size_t ws_size,
                              hipStream_t stream) {
    const float* pred = (const float*)d_in[0];
    const int* inst = (const int*)d_in[1];
    const unsigned char* msk = (const unsigned char*)d_in[2];
    float* out = (float*)d_out;
    float* ws = (float*)d_ws;
    unsigned char* idp = (unsigned char*)d_ws + IDP_OFF;

    k_zero<<<(NB * WS_S + 255) / 256, 256, 0, stream>>>(ws);
    dim3 agrid(ABLK, NB);
    k_accum<<<agrid, ATPB, 0, stream>>>(pred, inst, msk, ws, idp);
    k_centers<<<NB, 256, 0, stream>>>(ws);
    dim3 pgrid(PCHUNKS, NB);
    k_pull<<<pgrid, PTPB, 0, stream>>>(pred, idp, ws);
    k_final<<<1, 64, 0, stream>>>(ws, out);
}

// Round 5
// 111.079 us; speedup vs baseline: 4.5036x; 4.5036x over previous
//
#include <hip/hip_runtime.h>

typedef _Float16 half4 __attribute__((ext_vector_type(4)));
typedef float f32x4 __attribute__((ext_vector_type(4)));

#define NB 8
#define ND 32
#define NHW (512*512)
#define NK 16
#define IGN 255

// per-image stats workspace layout (floats)
#define WS_S   1088
#define O_CNT  0      // counts[16]
#define O_VPIX 16     // # of valid (mask & !=IGN) pixels
#define O_SUM  32     // sums[16*32], index = k*32 + d
#define O_CEN  544    // centers[16*32]
#define O_PULL 1056   // pull partial sums[16]
#define O_PUSH 1072
#define O_REG  1073
#define O_VB   1074
#define O_NID  1075

#define IDP_OFF 65536          // byte offset of packed-id region in ws

// accum: 1024 blocks, each 8 tiles of 256 px (2048 contiguous px)
#define ATPB 256
#define ABLK 128
#define TILE 256
#define NTILES 8
#define ROWP 260               // padded LDS row stride (floats): 1040B, 16B-aligned

// pull config
#define PTPB 256
#define PCHUNKS 256
#define PPIX (NHW / PCHUNKS)   // 1024

__global__ __launch_bounds__(256) void k_zero(float* __restrict__ ws) {
    int i = blockIdx.x * blockDim.x + threadIdx.x;
    if (i < NB * WS_S) ws[i] = 0.f;
}

// Pass 1: m97-style staged streaming + MFMA one-hot segment-sum.
// No LDS atomics in the hot loop.
__global__ __launch_bounds__(ATPB) void k_accum(const float* __restrict__ pred,
                                                const int* __restrict__ inst,
                                                const unsigned char* __restrict__ msk,
                                                float* __restrict__ ws,
                                                unsigned char* __restrict__ idp) {
    __shared__ __align__(16) float buf[2][ND][ROWP];   // 66.6 KB staging
    __shared__ float lcnt[NK + 2];
    const int tid = threadIdx.x;
    const int w = tid >> 6, l = tid & 63;
    const int dgrp = w & 1;        // d-group: d in [16*dgrp, 16*dgrp+16)
    const int phalf = w >> 1;      // pixel half of the 256-px tile
    const int b = blockIdx.y, chunk = blockIdx.x;

    if (tid < NK + 2) lcnt[tid] = 0.f;

    const size_t img = (size_t)b * NHW;
    const float* pb = pred + (size_t)b * ND * NHW;
    const int base0 = chunk * (NTILES * TILE);

#define STAGE(CUR, T)                                                         \
    {                                                                         \
        const int pix0_ = base0 + (T) * TILE;                                 \
        _Pragma("unroll")                                                     \
        for (int q_ = 0; q_ < 8; ++q_) {                                      \
            const int d_ = 8 * w + q_;                                        \
            const float* src_ = pb + (size_t)d_ * NHW + pix0_ + 4 * l;        \
            __builtin_amdgcn_global_load_lds(                                 \
                (const __attribute__((address_space(1))) unsigned*)src_,      \
                (__attribute__((address_space(3))) unsigned*)&buf[CUR][d_][0],\
                16, 0, 0);                                                    \
        }                                                                     \
    }

#define DECODE(IV, MV, PK, VC)                                                \
    {                                                                         \
        const int ia_[4] = {(IV).x, (IV).y, (IV).z, (IV).w};                  \
        (PK) = 0u;                                                            \
        _Pragma("unroll")                                                     \
        for (int p_ = 0; p_ < 4; ++p_) {                                      \
            const bool m_ = ((((MV) >> (8 * p_)) & 0xffu) != 0u) &&           \
                            (ia_[p_] != IGN);                                 \
            (VC) += m_ ? 1.f : 0.f;                                           \
            const unsigned s_ =                                               \
                (m_ && (unsigned)ia_[p_] < NK) ? (unsigned)ia_[p_] : NK;      \
            (PK) |= s_ << (8 * p_);                                           \
        }                                                                     \
    }

    // prologue: tile-0 ids + stage tile 0
    int4 iv = *(const int4*)(inst + img + base0 + 4 * l);
    unsigned mv = *(const unsigned*)(msk + img + base0 + 4 * l);
    STAGE(0, 0);
    unsigned pk;
    float vcnt = 0.f;
    DECODE(iv, mv, pk, vcnt);
    __syncthreads();   // compiler drains vmcnt -> tile 0 staged, lcnt zeroed

    f32x4 acc = {0.f, 0.f, 0.f, 0.f};
    for (int t = 0; t < NTILES; ++t) {
        const int cur = t & 1;
        int4 iv2;
        unsigned mv2 = 0;
        if (t + 1 < NTILES) {
            const int nb0 = base0 + (t + 1) * TILE;
            iv2 = *(const int4*)(inst + img + nb0 + 4 * l);
            mv2 = *(const unsigned*)(msk + img + nb0 + 4 * l);
            STAGE(cur ^ 1, t + 1);
        }
        // wave-0 bookkeeping for tile t (tiny; no pred data involved)
        if (w == 0) {
            uchar4 pkb = {(unsigned char)(pk & 0xff),
                          (unsigned char)((pk >> 8) & 0xff),
                          (unsigned char)((pk >> 16) & 0xff),
                          (unsigned char)(pk >> 24)};
            *(uchar4*)(idp + img + base0 + t * TILE + 4 * l) = pkb;
            #pragma unroll
            for (int p = 0; p < 4; ++p)
                atomicAdd(&lcnt[(pk >> (8 * p)) & 0xffu], 1.f);
        }
        // consume tile t: 8 K-steps of 16 px over this wave's 128-px half
        const int pxoff = phalf * 128;
        #pragma unroll
        for (int kk = 0; kk < 8; ++kk) {
            const f32x4 av = *(const f32x4*)
                &buf[cur][dgrp * 16 + (l & 15)][pxoff + kk * 16 + 4 * (l >> 4)];
            half4 ah;
            #pragma unroll
            for (int e = 0; e < 4; ++e) ah[e] = (_Float16)av[e];
            const int srcl = phalf * 32 + kk * 4 + (l >> 4);
            const unsigned pkk = (unsigned)__shfl((int)pk, srcl);
            half4 bh;
            #pragma unroll
            for (int e = 0; e < 4; ++e)
                bh[e] = (((pkk >> (8 * e)) & 0xffu) == (unsigned)(l & 15))
                            ? (_Float16)1.f : (_Float16)0.f;
            acc = __builtin_amdgcn_mfma_f32_16x16x16f16(ah, bh, acc, 0, 0, 0);
        }
        if (t + 1 < NTILES) DECODE(iv2, mv2, pk, vcnt);
        __syncthreads();   // drains stage(t+1); orders buffer reuse
    }
#undef STAGE
#undef DECODE

    // epilogue: acc holds sums_part[d = 4*(l>>4)+r][k = l&15] for (dgrp, phalf)
    float* sc = &buf[0][0][0];   // reuse staging as [4 wavegrp][16 d][16 k]
    const int widx = dgrp * 2 + phalf;
    #pragma unroll
    for (int r = 0; r < 4; ++r)
        sc[(widx * 16 + 4 * (l >> 4) + r) * 16 + (l & 15)] = acc[r];
    __syncthreads();

    float* wb = ws + b * WS_S;
    for (int i = tid; i < NK * ND; i += ATPB) {   // i = k*32 + d
        const int k = i >> 5, d = i & 31, dg = d >> 4, dr = d & 15;
        const float v = sc[((dg * 2 + 0) * 16 + dr) * 16 + k] +
                        sc[((dg * 2 + 1) * 16 + dr) * 16 + k];
        atomicAdd(&wb[O_SUM + i], v);
    }
    if (tid < NK) atomicAdd(&wb[O_CNT + tid], lcnt[tid]);
    if (w == 0) {
        #pragma unroll
        for (int off = 32; off > 0; off >>= 1) vcnt += __shfl_down(vcnt, off);
        if (l == 0) atomicAdd(&wb[O_VPIX], vcnt);
    }
}

__global__ __launch_bounds__(256) void k_centers(float* __restrict__ ws) {
    __shared__ float lc[NK][ND + 1];
    __shared__ float lcnt[NK];
    __shared__ float rsum[256], rcnt[256];
    const int tid = threadIdx.x;
    float* wb = ws + blockIdx.x * WS_S;

    if (tid < NK) lcnt[tid] = wb[O_CNT + tid];
    __syncthreads();
    for (int i = tid; i < NK * ND; i += 256) {
        int k = i >> 5, d = i & 31;
        float c = wb[O_SUM + i] / fmaxf(lcnt[k], 1.f);
        lc[k][d] = c;
        wb[O_CEN + i] = c;
    }
    __syncthreads();

    const int i = tid >> 4, j = tid & 15;
    const bool pm = (i != j) && (lcnt[i] > 0.f) && (lcnt[j] > 0.f);
    float sq = 0.f;
    #pragma unroll
    for (int d = 0; d < ND; ++d) { float df = lc[i][d] - lc[j][d]; sq += df * df; }
    float dm = sqrtf(pm ? sq : 1.f);
    float r = fmaxf(2.f * 1.5f - dm, 0.f);
    rsum[tid] = pm ? r * r : 0.f;
    rcnt[tid] = pm ? 1.f : 0.f;
    __syncthreads();
    for (int s = 128; s > 0; s >>= 1) {
        if (tid < s) { rsum[tid] += rsum[tid + s]; rcnt[tid] += rcnt[tid + s]; }
        __syncthreads();
    }

    if (tid == 0) {
        float nids = 0.f;
        for (int k = 0; k < NK; ++k) nids += (lcnt[k] > 0.f) ? 1.f : 0.f;
        float push = (nids > 1.f) ? rsum[0] / fmaxf(rcnt[0], 1.f) : 0.f;
        float reg = 0.f;
        for (int k = 0; k < NK; ++k) {
            if (lcnt[k] > 0.f) {
                float cs = 0.f;
                for (int d = 0; d < ND; ++d) cs += lc[k][d] * lc[k][d];
                reg += sqrtf(cs);
            }
        }
        reg /= fmaxf(nids, 1.f);
        wb[O_PUSH] = push;
        wb[O_REG] = reg;
        wb[O_VB] = (wb[O_VPIX] > 0.f) ? 1.f : 0.f;
        wb[O_NID] = nids;
    }
}

// Pass 2: float4 streaming + packed ids (measured fast; unchanged).
__global__ __launch_bounds__(PTPB) void k_pull(const float* __restrict__ pred,
                                               const unsigned char* __restrict__ idp,
                                               float* __restrict__ ws) {
    __shared__ float lc[17][ND + 1];   // row 16 = zeros (invalid)
    __shared__ float lp[2][NK];
    const int tid = threadIdx.x;
    // reversed global order vs k_accum: tail of pass-1 stream is L3-resident
    const int b = NB - 1 - blockIdx.y;
    const int chunk = PCHUNKS - 1 - blockIdx.x;
    const int half = (tid >> 5) & 1;
    float* wb = ws + b * WS_S;

    for (int i = tid; i < 17 * ND; i += PTPB)
        lc[i >> 5][i & 31] = (i < NK * ND) ? wb[O_CEN + i] : 0.f;
    if (tid < 2 * NK) ((float*)lp)[tid] = 0.f;
    __syncthreads();

    const size_t img = (size_t)b * NHW;
    const float* pb = pred + (size_t)b * ND * NHW;

    const int pix = chunk * PPIX + 4 * tid;
    const unsigned pk = *(const unsigned*)(idp + img + pix);
    const int id[4] = {(int)(pk & 0xff), (int)((pk >> 8) & 0xff),
                       (int)((pk >> 16) & 0xff), (int)(pk >> 24)};
    float sq[4] = {0.f, 0.f, 0.f, 0.f};
    #pragma unroll 8
    for (int d = 0; d < ND; ++d) {
        const float4 v = *(const float4*)(pb + (size_t)d * NHW + pix);
        float df0 = v.x - lc[id[0]][d];
        float df1 = v.y - lc[id[1]][d];
        float df2 = v.z - lc[id[2]][d];
        float df3 = v.w - lc[id[3]][d];
        sq[0] += df0 * df0; sq[1] += df1 * df1;
        sq[2] += df2 * df2; sq[3] += df3 * df3;
    }
    #pragma unroll
    for (int p = 0; p < 4; ++p) {
        if (id[p] < NK) {
            float r = fmaxf(sqrtf(sq[p]) - 0.5f, 0.f);
            atomicAdd(&lp[half][id[p]], r * r);
        }
    }
    __syncthreads();
    if (tid < NK) atomicAdd(&wb[O_PULL + tid], lp[0][tid] + lp[1][tid]);
}

__global__ void k_final(const float* __restrict__ ws, float* __restrict__ out) {
    const int tid = threadIdx.x;
    float contrib = 0.f, vb = 0.f;
    if (tid < NB) {
        const float* wb = ws + tid * WS_S;
        float nids = wb[O_NID];
        float pull = 0.f;
        for (int k = 0; k < NK; ++k) {
            float c = wb[O_CNT + k];
            if (c > 0.f) pull += wb[O_PULL + k] / fmaxf(c, 1.f);
        }
        pull /= fmaxf(nids, 1.f);
        vb = wb[O_VB];
        contrib = (pull + wb[O_PUSH] + 0.001f * wb[O_REG]) * vb;
    }
    #pragma unroll
    for (int off = 32; off > 0; off >>= 1) {
        contrib += __shfl_down(contrib, off);
        vb += __shfl_down(vb, off);
    }
    if (tid == 0) out[0] = (vb > 0.f) ? contrib / fmaxf(vb, 1.f) : 0.f;
}

extern "C" void kernel_launch(void* const* d_in, const int* in_sizes, int n_in,
                              void* d_out, int out_size, void* d_ws, size_t ws_size,
                              hipStream_t stream) {
    const float* pred = (const float*)d_in[0];
    const int* inst = (const int*)d_in[1];
    const unsigned char* msk = (const unsigned char*)d_in[2];
    float* out = (float*)d_out;
    float* ws = (float*)d_ws;
    unsigned char* idp = (unsigned char*)d_ws + IDP_OFF;

    k_zero<<<(NB * WS_S + 255) / 256, 256, 0, stream>>>(ws);
    dim3 agrid(ABLK, NB);
    k_accum<<<agrid, ATPB, 0, stream>>>(pred, inst, msk, ws, idp);
    k_centers<<<NB, 256, 0, stream>>>(ws);
    dim3 pgrid(PCHUNKS, NB);
    k_pull<<<pgrid, PTPB, 0, stream>>>(pred, idp, ws);
    k_final<<<1, 64, 0, stream>>>(ws, out);
}